// Round 15
// baseline (4509.583 us; speedup 1.0000x reference)
//
#include <hip/hip_runtime.h>
#include <cstdint>
#include <cstddef>

typedef _Float16 f16;
typedef _Float16 f16x8 __attribute__((ext_vector_type(8)));
typedef _Float16 f16x2 __attribute__((ext_vector_type(2)));
typedef float f32x4 __attribute__((ext_vector_type(4)));

#define B_ 64
#define I_ 128
#define H_ 256
#define T_ 1024
#define BT_ (B_*T_)

// ---------- helpers ----------
__device__ __forceinline__ uint32_t pack2_f16(float a, float b) {
  union { f16 h; uint16_t u; } ua, ub;
  ua.h = (f16)a; ub.h = (f16)b;
  return ((uint32_t)ub.u << 16) | (uint32_t)ua.u;
}

__device__ __forceinline__ float fdot2_u(uint32_t w, uint32_t x, float acc) {
  union { uint32_t u; f16x2 h; } uw, ux;
  uw.u = w; ux.u = x;
  return __builtin_amdgcn_fdot2(uw.h, ux.h, acc, false);
}

// stable tanh
__device__ __forceinline__ float tanh_stable(float s) {
  float a = fabsf(s);
  float e = __expf(-2.f * a);
  float t = (1.f - e) * __fdividef(1.f, 1.f + e);
  return s < 0.f ? -t : t;
}

__device__ __forceinline__ float sigmoidf(float s) {
  return __fdividef(1.f, 1.f + __expf(-s));
}

// MFMA fragment load (verified R3==R4)
__device__ __forceinline__ f16x8 load_frag(const f16* row, int k0, int g4) {
  union { uint32_t u[4]; f16x8 h; } r;
  const uint32_t* p0 = (const uint32_t*)(row + k0 + g4);
  const uint32_t* p1 = (const uint32_t*)(row + k0 + 16 + g4);
  r.u[0] = p0[0]; r.u[1] = p0[1];
  r.u[2] = p1[0]; r.u[3] = p1[1];
  return r.h;
}

// ---------- K0: transpose Delta [B,I,T] -> Dt f16 [B,T,I] ----------
__global__ void k_transpose_d(const float* __restrict__ D, f16* __restrict__ Dt) {
  __shared__ float tile[64][65];
  int t0 = blockIdx.x * 64, i0 = blockIdx.y * 64, b = blockIdx.z;
  int tx = threadIdx.x, ty = threadIdx.y;  // 64 x 4
  #pragma unroll
  for (int r = 0; r < 16; ++r) {
    int il = ty + r * 4;
    tile[il][tx] = D[((size_t)(b * I_ + i0 + il)) * T_ + t0 + tx];
  }
  __syncthreads();
  #pragma unroll
  for (int r = 0; r < 16; ++r) {
    int tl = ty + r * 4;
    Dt[((size_t)(b * T_ + t0 + tl)) * I_ + i0 + tx] = (f16)tile[tx][tl];
  }
}

// ---------- K_w: weight prep for 256-thread full-row-ownership recurrence ----------
// blobR  [c<128][t<256]: pack(Whr[t][2c], Whr[t][2c+1])              (regs)
// blobHr [c<104][t<256]: pack(Whh[t][2c], Whh[t][2c+1])  k<208      (regs)
// blobZ  [(kb<32)*256+t][q<4]: pack(Whz[t][kb*8+2q], [+1])          (LDS, kb-major)
// blobHs [(kb<6)*256+t][q<4]:  pack(Whh[t][208+kb*8+2q], [+1])      (LDS sliver)
__global__ void k_prep(const float* __restrict__ Wdgx, const float* __restrict__ bdgx,
                       const float* __restrict__ Wdgh, const float* __restrict__ bdgh,
                       const float* __restrict__ Wxz, const float* __restrict__ Whz,
                       const float* __restrict__ Wmz, const float* __restrict__ bmz,
                       const float* __restrict__ Wxr, const float* __restrict__ Whr,
                       const float* __restrict__ Wmr,
                       const float* __restrict__ Wxh, const float* __restrict__ Whh,
                       const float* __restrict__ Wmh, const float* __restrict__ bmh,
                       f16* __restrict__ Wg, float* __restrict__ bg,
                       f16* __restrict__ W3, float* __restrict__ b3,
                       uint32_t* __restrict__ blobR, uint32_t* __restrict__ blobHr,
                       uint32_t* __restrict__ blobZ, uint32_t* __restrict__ blobHs) {
  int tid = blockIdx.x * blockDim.x + threadIdx.x;
  int nth = gridDim.x * blockDim.x;
  // Wg [384][128]: rows 0-127 Wdgx, 128-383 Wdgh
  for (int idx = tid; idx < 384 * 128; idx += nth) {
    int j = idx >> 7, k = idx & 127;
    float v = (j < 128) ? Wdgx[j * 128 + k] : Wdgh[(j - 128) * 128 + k];
    Wg[idx] = (f16)v;
  }
  for (int j = tid; j < 384; j += nth) bg[j] = (j < 128) ? bdgx[j] : bdgh[j - 128];
  // W3 [768][256]
  for (int idx = tid; idx < 768 * 256; idx += nth) {
    int j = idx >> 8, c = idx & 255;
    const float* Wx = (j < 256) ? Wxz : ((j < 512) ? Wxr : Wxh);
    const float* Wm = (j < 256) ? Wmz : ((j < 512) ? Wmr : Wmh);
    int jj = j & 255;
    float v = (c < 128) ? Wx[jj * 128 + c] : Wm[jj * 128 + (c - 128)];
    W3[idx] = (f16)v;
  }
  for (int j = tid; j < 768; j += nth)
    b3[j] = (j < 256) ? bmz[j] : ((j < 512) ? 0.0f : bmh[j - 512]);
  // blobR: Whr full rows
  for (int idx = tid; idx < 128 * 256; idx += nth) {
    int c = idx >> 8, t = idx & 255;
    blobR[idx] = pack2_f16(Whr[t * 256 + 2 * c], Whr[t * 256 + 2 * c + 1]);
  }
  // blobHr: Whh k<208
  for (int idx = tid; idx < 104 * 256; idx += nth) {
    int c = idx >> 8, t = idx & 255;
    blobHr[idx] = pack2_f16(Whh[t * 256 + 2 * c], Whh[t * 256 + 2 * c + 1]);
  }
  // blobZ: Whz kb-major uint4
  for (int idx = tid; idx < 32 * 256 * 4; idx += nth) {
    int q = idx & 3, r = idx >> 2;
    int t = r & 255, kb = r >> 8;
    int k = kb * 8 + 2 * q;
    blobZ[idx] = pack2_f16(Whz[t * 256 + k], Whz[t * 256 + k + 1]);
  }
  // blobHs: Whh sliver k in [208,256)
  for (int idx = tid; idx < 6 * 256 * 4; idx += nth) {
    int q = idx & 3, r = idx >> 2;
    int t = r & 255, kb = r >> 8;
    int k = 208 + kb * 8 + 2 * q;
    blobHs[idx] = pack2_f16(Whh[t * 256 + k], Whh[t * 256 + k + 1]);
  }
}

// ---------- K1 (MFMA): Gx/Gh = exp(-relu(Dt @ Wg^T + bg)) ----------
__global__ __launch_bounds__(256) void k_gemm1(const f16* __restrict__ A,
                                               const f16* __restrict__ W,
                                               const float* __restrict__ bias,
                                               float* __restrict__ Gx,
                                               f16* __restrict__ Gh) {
  __shared__ __align__(16) f16 As[64][136];
  __shared__ __align__(16) f16 Ws[128][136];
  int m0 = blockIdx.x * 64, n0 = blockIdx.y * 128;
  int tid = threadIdx.x;
  {
    int r = tid >> 2, sgm = tid & 3;
    const uint4* src = (const uint4*)(A + (size_t)(m0 + r) * 128 + sgm * 32);
    uint4* dst = (uint4*)(&As[r][sgm * 32]);
    #pragma unroll
    for (int q = 0; q < 4; ++q) dst[q] = src[q];
  }
  {
    int r = tid >> 1, hf = tid & 1;
    const uint4* src = (const uint4*)(W + (size_t)(n0 + r) * 128 + hf * 64);
    uint4* dst = (uint4*)(&Ws[r][hf * 64]);
    #pragma unroll
    for (int q = 0; q < 8; ++q) dst[q] = src[q];
  }
  __syncthreads();
  int w = tid >> 6, l = tid & 63;
  int lr = l & 15, g4 = (l >> 4) * 4;
  f32x4 acc[8] = {};
  #pragma unroll
  for (int kk = 0; kk < 4; ++kk) {
    int k0 = kk * 32;
    f16x8 a = load_frag(&As[w * 16 + lr][0], k0, g4);
    #pragma unroll
    for (int nt = 0; nt < 8; ++nt) {
      f16x8 bf = load_frag(&Ws[nt * 16 + lr][0], k0, g4);
      acc[nt] = __builtin_amdgcn_mfma_f32_16x16x32_f16(a, bf, acc[nt], 0, 0, 0);
    }
  }
  int row4 = (l >> 4) * 4;
  #pragma unroll
  for (int nt = 0; nt < 8; ++nt) {
    int n = n0 + nt * 16 + lr;
    float bv = bias[n];
    #pragma unroll
    for (int reg = 0; reg < 4; ++reg) {
      int m = m0 + w * 16 + row4 + reg;
      float s = acc[nt][reg] + bv;
      float g = __expf(-fmaxf(s, 0.0f));
      if (n < 128) Gx[(size_t)m * 128 + n] = g;
      else         Gh[(size_t)m * 256 + (n - 128)] = (f16)g;
    }
  }
}

// ---------- K3 (MFMA): P = AC @ W3^T + b3 (f16 out) ----------
__global__ __launch_bounds__(256) void k_gemm3(const f16* __restrict__ A,
                                               const f16* __restrict__ W,
                                               const float* __restrict__ bias,
                                               f16* __restrict__ P) {
  __shared__ __align__(16) f16 As[64][136];
  __shared__ __align__(16) f16 Ws[128][136];
  int m0 = blockIdx.x * 64, n0 = blockIdx.y * 128;
  int tid = threadIdx.x;
  int w = tid >> 6, l = tid & 63, lr = l & 15, g4 = (l >> 4) * 4;
  f32x4 acc[8] = {};
  for (int kh = 0; kh < 2; ++kh) {
    {
      int r = tid >> 2, sgm = tid & 3;
      const uint4* src = (const uint4*)(A + (size_t)(m0 + r) * 256 + kh * 128 + sgm * 32);
      uint4* dst = (uint4*)(&As[r][sgm * 32]);
      #pragma unroll
      for (int q = 0; q < 4; ++q) dst[q] = src[q];
    }
    {
      int r = tid >> 1, hf = tid & 1;
      const uint4* src = (const uint4*)(W + (size_t)(n0 + r) * 256 + kh * 128 + hf * 64);
      uint4* dst = (uint4*)(&Ws[r][hf * 64]);
      #pragma unroll
      for (int q = 0; q < 8; ++q) dst[q] = src[q];
    }
    __syncthreads();
    #pragma unroll
    for (int kk = 0; kk < 4; ++kk) {
      int k0 = kk * 32;
      f16x8 a = load_frag(&As[w * 16 + lr][0], k0, g4);
      #pragma unroll
      for (int nt = 0; nt < 8; ++nt) {
        f16x8 bf = load_frag(&Ws[nt * 16 + lr][0], k0, g4);
        acc[nt] = __builtin_amdgcn_mfma_f32_16x16x32_f16(a, bf, acc[nt], 0, 0, 0);
      }
    }
    __syncthreads();
  }
  int row4 = (l >> 4) * 4;
  #pragma unroll
  for (int nt = 0; nt < 8; ++nt) {
    int n = n0 + nt * 16 + lr;
    float bv = bias[n];
    #pragma unroll
    for (int reg = 0; reg < 4; ++reg) {
      int m = m0 + w * 16 + row4 + reg;
      P[(size_t)m * 768 + n] = (f16)(acc[nt][reg] + bv);
    }
  }
}

// ---------- K2a: per-segment last-observation summaries ----------
__global__ void k_seg(const float* __restrict__ X, const float* __restrict__ M,
                      float* __restrict__ segX, float* __restrict__ segF) {
  int b = blockIdx.x, s = blockIdx.y, i = threadIdx.x;
  const float* xr = X + ((size_t)(b * I_ + i)) * T_ + s * 128;
  const float* mr = M + ((size_t)(b * I_ + i)) * T_ + s * 128;
  float last = 0.f, seen = 0.f;
  for (int t = 0; t < 128; ++t) {
    float m = mr[t];
    float x = xr[t];
    if (m > 0.f) { last = x; seen = 1.f; }
  }
  segX[((size_t)(b * I_ + i)) * 8 + s] = last;
  segF[((size_t)(b * I_ + i)) * 8 + s] = seen;
}

// ---------- K2b: x_last + double imputation -> AC f16 [BT][256] = [x2 | m] ----------
__global__ void k_x2(const float* __restrict__ X, const float* __restrict__ M,
                     const float* __restrict__ Gx, const float* __restrict__ xmean_p,
                     const float* __restrict__ segX, const float* __restrict__ segF,
                     f16* __restrict__ AC) {
  int b = blockIdx.x, s = blockIdx.y, i = threadIdx.x;
  float xm = xmean_p[0];
  float xl = 0.f;
  const float* sF = segF + ((size_t)(b * I_ + i)) * 8;
  const float* sX = segX + ((size_t)(b * I_ + i)) * 8;
  for (int p = 0; p < s; ++p) { if (sF[p] > 0.f) xl = sX[p]; }
  const float* xr = X + ((size_t)(b * I_ + i)) * T_;
  const float* mr = M + ((size_t)(b * I_ + i)) * T_;
  for (int tl = 0; tl < 128; ++tl) {
    int t = s * 128 + tl;
    float x = xr[t], m = mr[t];
    float gx = Gx[((size_t)(b * T_ + t)) * I_ + i];
    if (m > 0.f) xl = x;  // x_last updated BEFORE imputation (ref order)
    float x1 = m * x + (1.f - m) * (gx * x + (1.f - gx) * xm);
    float x2 = m * x1 + (1.f - m) * (gx * xl + (1.f - gx) * xm);
    size_t o = ((size_t)(b * T_ + t)) * 256;
    AC[o + i] = (f16)x2;
    AC[o + 128 + i] = (f16)m;
  }
}

// ---------- K4: recurrence, 256 threads, full-row ownership ----------
// Allocator law (R7-R14): allocated VGPR = 65536/threads. 256 threads -> 256
// budget (m97 precedent: 164+64 at 256thr). Thread tid owns OUTPUT ROW tid of
// all three matrices -> no cross-thread partials, 2 barriers/step.
// Regs: Whr row (128 u32) + Whh row k<208 (104 u32) = 232.
// LDS (kb-major uint4 [kb][row] -> lanes read consecutive 16B, conflict-free):
//   Whz 128 KB + Whh k>=208 sliver 24 KB + hdh ping-pong + rhdh ~ 157 KB.
// 1 wave/SIMD: 4 independent accumulators per dot to pipeline fdot2 latency.
#define RSTEP(curH, nxtH, IT)                                              \
  {                                                                        \
    float pz_n = 0.f, pr_n = 0.f, ph_n = 0.f, gh_n = 0.f;                  \
    if ((IT) + 1 < T_) {                                                   \
      pz_n = (float)pnext[0];                                              \
      pr_n = (float)pnext[256];                                            \
      ph_n = (float)pnext[512];                                            \
    }                                                                      \
    if ((IT) + 2 < T_) gh_n = (float)gnext[0];                             \
    pnext += 768; gnext += 256;                                            \
    const uint4* h4 = (const uint4*)(curH);                                \
    float r0 = 0.f, r1 = 0.f, r2 = 0.f, r3 = 0.f;                          \
    float z0 = 0.f, z1 = 0.f, z2 = 0.f, z3 = 0.f;                          \
    _Pragma("unroll")                                                      \
    for (int c4 = 0; c4 < 32; ++c4) {                                      \
      uint4 hv = h4[c4];                                                   \
      uint4 wz = whz_l[c4 * 256 + tid];                                    \
      r0 = fdot2_u(wr[c4 * 4 + 0], hv.x, r0);                              \
      r1 = fdot2_u(wr[c4 * 4 + 1], hv.y, r1);                              \
      r2 = fdot2_u(wr[c4 * 4 + 2], hv.z, r2);                              \
      r3 = fdot2_u(wr[c4 * 4 + 3], hv.w, r3);                              \
      z0 = fdot2_u(wz.x, hv.x, z0);                                        \
      z1 = fdot2_u(wz.y, hv.y, z1);                                        \
      z2 = fdot2_u(wz.z, hv.z, z2);                                        \
      z3 = fdot2_u(wz.w, hv.w, z3);                                        \
    }                                                                      \
    float rr = sigmoidf(pr_c + ((r0 + r1) + (r2 + r3)));                   \
    rhdh[tid] = (f16)(rr * hd_own);                                        \
    __syncthreads(); /* B1: rhdh ready */                                  \
    const uint4* rh4 = (const uint4*)rhdh;                                 \
    float t0 = 0.f, t1 = 0.f, t2 = 0.f, t3 = 0.f;                          \
    _Pragma("unroll")                                                      \
    for (int c4 = 0; c4 < 26; ++c4) {                                      \
      uint4 rv = rh4[c4];                                                  \
      t0 = fdot2_u(wh[c4 * 4 + 0], rv.x, t0);                              \
      t1 = fdot2_u(wh[c4 * 4 + 1], rv.y, t1);                              \
      t2 = fdot2_u(wh[c4 * 4 + 2], rv.z, t2);                              \
      t3 = fdot2_u(wh[c4 * 4 + 3], rv.w, t3);                              \
    }                                                                      \
    _Pragma("unroll")                                                      \
    for (int c4 = 26; c4 < 32; ++c4) {                                     \
      uint4 rv = rh4[c4];                                                  \
      uint4 wv = whh_l[(c4 - 26) * 256 + tid];                             \
      t0 = fdot2_u(wv.x, rv.x, t0);                                        \
      t1 = fdot2_u(wv.y, rv.y, t1);                                        \
      t2 = fdot2_u(wv.z, rv.z, t2);                                        \
      t3 = fdot2_u(wv.w, rv.w, t3);                                        \
    }                                                                      \
    float zz = sigmoidf(pz_c + ((z0 + z1) + (z2 + z3)));                   \
    float ht = tanh_stable(ph_c + ((t0 + t1) + (t2 + t3)));                \
    float hnew = (1.f - zz) * hd_own + zz * ht;                            \
    outp[0] = hnew;                                                        \
    outp += 256;                                                           \
    hd_own = gh_u * hnew;                                                  \
    (nxtH)[tid] = (f16)hd_own;                                             \
    pz_c = pz_n; pr_c = pr_n; ph_c = ph_n; gh_u = gh_n;                    \
    __syncthreads(); /* B2: nxtH ready */                                  \
  }

__global__ __launch_bounds__(256, 1) void k_recur9(
    const f16* __restrict__ Gh, const f16* __restrict__ P,
    const uint32_t* __restrict__ blobR, const uint32_t* __restrict__ blobHr,
    const uint32_t* __restrict__ blobZ, const uint32_t* __restrict__ blobHs,
    float* __restrict__ out) {
  __shared__ __align__(16) uint4 whz_l[32 * 256];   // 131072 B
  __shared__ __align__(16) uint4 whh_l[6 * 256];    //  24576 B
  __shared__ __align__(16) f16 hdhA[256];
  __shared__ __align__(16) f16 hdhB[256];
  __shared__ __align__(16) f16 rhdh[256];
  int tid = threadIdx.x;
  int b = blockIdx.x;

  // stage LDS weights (coalesced uint4)
  #pragma unroll
  for (int i = 0; i < 32; ++i) whz_l[i * 256 + tid] = ((const uint4*)blobZ)[i * 256 + tid];
  #pragma unroll
  for (int i = 0; i < 6; ++i)  whh_l[i * 256 + tid] = ((const uint4*)blobHs)[i * 256 + tid];

  uint32_t wr[128], wh[104];
  #pragma unroll
  for (int c = 0; c < 128; ++c) wr[c] = blobR[c * 256 + tid];
  #pragma unroll
  for (int c = 0; c < 104; ++c) wh[c] = blobHr[c * 256 + tid];

  const f16* gbase = Gh + (size_t)b * T_ * 256;
  const f16* pbase = P + (size_t)b * T_ * 768;
  float* outp = out + (size_t)b * T_ * 256 + tid;

  float hd_own = 0.f;                              // hd(0) = gamma(0)*h0 = 0
  float pz_c = (float)pbase[tid];
  float pr_c = (float)pbase[256 + tid];
  float ph_c = (float)pbase[512 + tid];
  float gh_u = (float)gbase[256 + tid];            // gamma(1)
  const f16* pnext = pbase + 768 + tid;            // P[it+1]
  const f16* gnext = gbase + 512 + tid;            // gamma(it+2)
  hdhA[tid] = (f16)0.f;
  __syncthreads();

  for (int it = 0; it < T_; it += 2) {
    RSTEP(hdhA, hdhB, it)
    RSTEP(hdhB, hdhA, it + 1)
  }
}

// ---------- workspace layout ----------
static constexpr size_t OFF_P  = 0;                          // f16 [BT][768]  = 100663296 B
static constexpr size_t OFF_DT = 0;                          // f16 [BT][128]  (overlay; dead before K3)
static constexpr size_t OFF_GX = 100663296;                  // f32 [BT][128]  = 33554432
static constexpr size_t OFF_GH = OFF_GX + 33554432;          // f16 [BT][256]  = 33554432
static constexpr size_t OFF_AC = OFF_GH + 33554432;          // f16 [BT][256]  = 33554432
static constexpr size_t OFF_WG = OFF_AC + 33554432;          // f16 [384][128] = 98304
static constexpr size_t OFF_BG = OFF_WG + 98304;             // f32 [384]      = 1536
static constexpr size_t OFF_W3 = OFF_BG + 1536;              // f16 [768][256] = 393216
static constexpr size_t OFF_B3 = OFF_W3 + 393216;            // f32 [768]      = 3072
static constexpr size_t OFF_BR = OFF_B3 + 3072;              // u32 [128][256] = 131072
static constexpr size_t OFF_BH = OFF_BR + 131072;            // u32 [104][256] = 106496
static constexpr size_t OFF_BZ = OFF_BH + 106496;            // u32 [32*256*4] = 131072
static constexpr size_t OFF_BS = OFF_BZ + 131072;            // u32 [6*256*4]  = 24576
static constexpr size_t OFF_SX = OFF_BS + 24576;             // f32 [B][I][8]  = 262144
static constexpr size_t OFF_SF = OFF_SX + 262144;            // f32 [B][I][8]  = 262144
static constexpr size_t WS_TOTAL = OFF_SF + 262144;          // ~193.6 MiB

extern "C" void kernel_launch(void* const* d_in, const int* in_sizes, int n_in,
                              void* d_out, int out_size, void* d_ws, size_t ws_size,
                              hipStream_t stream) {
  const float* X    = (const float*)d_in[0];
  const float* Mask = (const float*)d_in[1];
  const float* Delta= (const float*)d_in[2];
  const float* xm   = (const float*)d_in[3];
  const float* Wdgx = (const float*)d_in[4];
  const float* bdgx = (const float*)d_in[5];
  const float* Wdgh = (const float*)d_in[6];
  const float* bdgh = (const float*)d_in[7];
  const float* Wxz  = (const float*)d_in[8];
  const float* Whz  = (const float*)d_in[9];
  const float* Wmz  = (const float*)d_in[10];
  const float* bmz  = (const float*)d_in[11];
  const float* Wxr  = (const float*)d_in[12];
  const float* Whr  = (const float*)d_in[13];
  const float* Wmr  = (const float*)d_in[14];
  const float* Wxh  = (const float*)d_in[15];
  const float* Whh  = (const float*)d_in[16];
  const float* Wmh  = (const float*)d_in[17];
  const float* bmh  = (const float*)d_in[18];
  float* out = (float*)d_out;   // f32 output (reference returns float32)
  char* ws = (char*)d_ws;
  if (ws_size < WS_TOTAL) return;  // insufficient scratch: bail cleanly

  f16*      Dt   = (f16*)(ws + OFF_DT);
  f16*      P    = (f16*)(ws + OFF_P);
  float*    Gx   = (float*)(ws + OFF_GX);
  f16*      Gh   = (f16*)(ws + OFF_GH);
  f16*      AC   = (f16*)(ws + OFF_AC);
  f16*      Wg   = (f16*)(ws + OFF_WG);
  float*    bg   = (float*)(ws + OFF_BG);
  f16*      W3   = (f16*)(ws + OFF_W3);
  float*    b3   = (float*)(ws + OFF_B3);
  uint32_t* blR  = (uint32_t*)(ws + OFF_BR);
  uint32_t* blH  = (uint32_t*)(ws + OFF_BH);
  uint32_t* blZ  = (uint32_t*)(ws + OFF_BZ);
  uint32_t* blS  = (uint32_t*)(ws + OFF_BS);
  float*    segX = (float*)(ws + OFF_SX);
  float*    segF = (float*)(ws + OFF_SF);

  k_prep<<<dim3(64), dim3(256), 0, stream>>>(Wdgx, bdgx, Wdgh, bdgh, Wxz, Whz, Wmz, bmz,
                                             Wxr, Whr, Wmr, Wxh, Whh, Wmh, bmh,
                                             Wg, bg, W3, b3, blR, blH, blZ, blS);
  k_transpose_d<<<dim3(16, 2, 64), dim3(64, 4), 0, stream>>>(Delta, Dt);
  k_gemm1<<<dim3(1024, 3), dim3(256), 0, stream>>>(Dt, Wg, bg, Gx, Gh);
  k_seg<<<dim3(64, 8), dim3(128), 0, stream>>>(X, Mask, segX, segF);
  k_x2<<<dim3(64, 8), dim3(128), 0, stream>>>(X, Mask, Gx, xm, segX, segF, AC);
  k_gemm3<<<dim3(1024, 6), dim3(256), 0, stream>>>(AC, W3, b3, P);
  k_recur9<<<dim3(64), dim3(256), 0, stream>>>(Gh, P, blR, blH, blZ, blS, out);
}

// Round 16
// 2216.646 us; speedup vs baseline: 2.0344x; 2.0344x over previous
//
#include <hip/hip_runtime.h>
#include <cstdint>
#include <cstddef>

typedef _Float16 f16;
typedef _Float16 f16x8 __attribute__((ext_vector_type(8)));
typedef _Float16 f16x2 __attribute__((ext_vector_type(2)));
typedef float f32x4 __attribute__((ext_vector_type(4)));

#define B_ 64
#define I_ 128
#define H_ 256
#define T_ 1024
#define BT_ (B_*T_)

// ---------- helpers ----------
__device__ __forceinline__ uint32_t pack2_f16(float a, float b) {
  union { f16 h; uint16_t u; } ua, ub;
  ua.h = (f16)a; ub.h = (f16)b;
  return ((uint32_t)ub.u << 16) | (uint32_t)ua.u;
}

__device__ __forceinline__ float fdot2_u(uint32_t w, uint32_t x, float acc) {
  union { uint32_t u; f16x2 h; } uw, ux;
  uw.u = w; ux.u = x;
  return __builtin_amdgcn_fdot2(uw.h, ux.h, acc, false);
}

__device__ __forceinline__ float tanh_stable(float s) {
  float a = fabsf(s);
  float e = __expf(-2.f * a);
  float t = (1.f - e) * __fdividef(1.f, 1.f + e);
  return s < 0.f ? -t : t;
}

__device__ __forceinline__ float sigmoidf(float s) {
  return __fdividef(1.f, 1.f + __expf(-s));
}

// MFMA fragment load (verified R3==R4)
__device__ __forceinline__ f16x8 load_frag(const f16* row, int k0, int g4) {
  union { uint32_t u[4]; f16x8 h; } r;
  const uint32_t* p0 = (const uint32_t*)(row + k0 + g4);
  const uint32_t* p1 = (const uint32_t*)(row + k0 + 16 + g4);
  r.u[0] = p0[0]; r.u[1] = p0[1];
  r.u[2] = p1[0]; r.u[3] = p1[1];
  return r.h;
}

// ---------- K0: transpose Delta [B,I,T] -> Dt f16 [B,T,I] ----------
__global__ void k_transpose_d(const float* __restrict__ D, f16* __restrict__ Dt) {
  __shared__ float tile[64][65];
  int t0 = blockIdx.x * 64, i0 = blockIdx.y * 64, b = blockIdx.z;
  int tx = threadIdx.x, ty = threadIdx.y;  // 64 x 4
  #pragma unroll
  for (int r = 0; r < 16; ++r) {
    int il = ty + r * 4;
    tile[il][tx] = D[((size_t)(b * I_ + i0 + il)) * T_ + t0 + tx];
  }
  __syncthreads();
  #pragma unroll
  for (int r = 0; r < 16; ++r) {
    int tl = ty + r * 4;
    Dt[((size_t)(b * T_ + t0 + tl)) * I_ + i0 + tx] = (f16)tile[tx][tl];
  }
}

// ---------- K_w: weight prep ----------
// Thread model for k_recur10 (512 thr): ks=t>>7, rg=t&127, rows r0=2rg, r1=2rg+1,
// k-slice K=[64ks, 64ks+64).
// blobR   [c<64][t]:  Whr regs; c=rr*32+cc -> row 2rg+rr, k=64ks+2cc.
// blobHrg [c<56][t]:  Whh regs; c=rr*28+cc -> row 2rg+rr, k=64ks+2cc (cc<28).
// blobZ4  [(c4<16)*512+t][q<4]: Whz LDS; c4=rr*8+qq -> row 2rg+rr, k=64ks+qq*8+2q.
// blobHl4 [(c4<2)*512+t][q<4]:  Whh LDS sliver; c4=rr -> row 2rg+rr, k=64ks+56+2q.
__global__ void k_prep(const float* __restrict__ Wdgx, const float* __restrict__ bdgx,
                       const float* __restrict__ Wdgh, const float* __restrict__ bdgh,
                       const float* __restrict__ Wxz, const float* __restrict__ Whz,
                       const float* __restrict__ Wmz, const float* __restrict__ bmz,
                       const float* __restrict__ Wxr, const float* __restrict__ Whr,
                       const float* __restrict__ Wmr,
                       const float* __restrict__ Wxh, const float* __restrict__ Whh,
                       const float* __restrict__ Wmh, const float* __restrict__ bmh,
                       f16* __restrict__ Wg, float* __restrict__ bg,
                       f16* __restrict__ W3, float* __restrict__ b3,
                       uint32_t* __restrict__ blobR, uint32_t* __restrict__ blobHrg,
                       uint32_t* __restrict__ blobZ4, uint32_t* __restrict__ blobHl4) {
  int tid = blockIdx.x * blockDim.x + threadIdx.x;
  int nth = gridDim.x * blockDim.x;
  // Wg [384][128]
  for (int idx = tid; idx < 384 * 128; idx += nth) {
    int j = idx >> 7, k = idx & 127;
    float v = (j < 128) ? Wdgx[j * 128 + k] : Wdgh[(j - 128) * 128 + k];
    Wg[idx] = (f16)v;
  }
  for (int j = tid; j < 384; j += nth) bg[j] = (j < 128) ? bdgx[j] : bdgh[j - 128];
  // W3 [768][256]
  for (int idx = tid; idx < 768 * 256; idx += nth) {
    int j = idx >> 8, c = idx & 255;
    const float* Wx = (j < 256) ? Wxz : ((j < 512) ? Wxr : Wxh);
    const float* Wm = (j < 256) ? Wmz : ((j < 512) ? Wmr : Wmh);
    int jj = j & 255;
    float v = (c < 128) ? Wx[jj * 128 + c] : Wm[jj * 128 + (c - 128)];
    W3[idx] = (f16)v;
  }
  for (int j = tid; j < 768; j += nth)
    b3[j] = (j < 256) ? bmz[j] : ((j < 512) ? 0.0f : bmh[j - 512]);
  // blobR: Whr regs
  for (int idx = tid; idx < 64 * 512; idx += nth) {
    int c = idx >> 9, t = idx & 511;
    int rr = c >> 5, cc = c & 31;
    int ks = t >> 7, rg = t & 127;
    int row = rg * 2 + rr;
    int k = ks * 64 + cc * 2;
    blobR[idx] = pack2_f16(Whr[row * 256 + k], Whr[row * 256 + k + 1]);
  }
  // blobHrg: Whh regs (k-offset < 56 within slice)
  for (int idx = tid; idx < 56 * 512; idx += nth) {
    int c = idx >> 9, t = idx & 511;
    int rr = (c >= 28) ? 1 : 0, cc = c - rr * 28;
    int ks = t >> 7, rg = t & 127;
    int row = rg * 2 + rr;
    int k = ks * 64 + cc * 2;
    blobHrg[idx] = pack2_f16(Whh[row * 256 + k], Whh[row * 256 + k + 1]);
  }
  // blobZ4: Whz LDS image (uint4-ordered)
  for (int idx = tid; idx < 16 * 512 * 4; idx += nth) {
    int q = idx & 3, r = idx >> 2;
    int t = r & 511, c4 = r >> 9;
    int rr = c4 >> 3, qq = c4 & 7;
    int ks = t >> 7, rg = t & 127;
    int row = rg * 2 + rr;
    int k = ks * 64 + qq * 8 + q * 2;
    blobZ4[idx] = pack2_f16(Whz[row * 256 + k], Whz[row * 256 + k + 1]);
  }
  // blobHl4: Whh LDS sliver (k in [64ks+56, 64ks+64))
  for (int idx = tid; idx < 2 * 512 * 4; idx += nth) {
    int q = idx & 3, r = idx >> 2;
    int t = r & 511, rr = r >> 9;
    int ks = t >> 7, rg = t & 127;
    int row = rg * 2 + rr;
    int k = ks * 64 + 56 + q * 2;
    blobHl4[idx] = pack2_f16(Whh[row * 256 + k], Whh[row * 256 + k + 1]);
  }
}

// ---------- K1 (MFMA): Gx/Gh = exp(-relu(Dt @ Wg^T + bg)) ----------
__global__ __launch_bounds__(256) void k_gemm1(const f16* __restrict__ A,
                                               const f16* __restrict__ W,
                                               const float* __restrict__ bias,
                                               float* __restrict__ Gx,
                                               f16* __restrict__ Gh) {
  __shared__ __align__(16) f16 As[64][136];
  __shared__ __align__(16) f16 Ws[128][136];
  int m0 = blockIdx.x * 64, n0 = blockIdx.y * 128;
  int tid = threadIdx.x;
  {
    int r = tid >> 2, sgm = tid & 3;
    const uint4* src = (const uint4*)(A + (size_t)(m0 + r) * 128 + sgm * 32);
    uint4* dst = (uint4*)(&As[r][sgm * 32]);
    #pragma unroll
    for (int q = 0; q < 4; ++q) dst[q] = src[q];
  }
  {
    int r = tid >> 1, hf = tid & 1;
    const uint4* src = (const uint4*)(W + (size_t)(n0 + r) * 128 + hf * 64);
    uint4* dst = (uint4*)(&Ws[r][hf * 64]);
    #pragma unroll
    for (int q = 0; q < 8; ++q) dst[q] = src[q];
  }
  __syncthreads();
  int w = tid >> 6, l = tid & 63;
  int lr = l & 15, g4 = (l >> 4) * 4;
  f32x4 acc[8] = {};
  #pragma unroll
  for (int kk = 0; kk < 4; ++kk) {
    int k0 = kk * 32;
    f16x8 a = load_frag(&As[w * 16 + lr][0], k0, g4);
    #pragma unroll
    for (int nt = 0; nt < 8; ++nt) {
      f16x8 bf = load_frag(&Ws[nt * 16 + lr][0], k0, g4);
      acc[nt] = __builtin_amdgcn_mfma_f32_16x16x32_f16(a, bf, acc[nt], 0, 0, 0);
    }
  }
  int row4 = (l >> 4) * 4;
  #pragma unroll
  for (int nt = 0; nt < 8; ++nt) {
    int n = n0 + nt * 16 + lr;
    float bv = bias[n];
    #pragma unroll
    for (int reg = 0; reg < 4; ++reg) {
      int m = m0 + w * 16 + row4 + reg;
      float s = acc[nt][reg] + bv;
      float g = __expf(-fmaxf(s, 0.0f));
      if (n < 128) Gx[(size_t)m * 128 + n] = g;
      else         Gh[(size_t)m * 256 + (n - 128)] = (f16)g;
    }
  }
}

// ---------- K3 (MFMA): P = AC @ W3^T + b3 (f16 out) ----------
__global__ __launch_bounds__(256) void k_gemm3(const f16* __restrict__ A,
                                               const f16* __restrict__ W,
                                               const float* __restrict__ bias,
                                               f16* __restrict__ P) {
  __shared__ __align__(16) f16 As[64][136];
  __shared__ __align__(16) f16 Ws[128][136];
  int m0 = blockIdx.x * 64, n0 = blockIdx.y * 128;
  int tid = threadIdx.x;
  int w = tid >> 6, l = tid & 63, lr = l & 15, g4 = (l >> 4) * 4;
  f32x4 acc[8] = {};
  for (int kh = 0; kh < 2; ++kh) {
    {
      int r = tid >> 2, sgm = tid & 3;
      const uint4* src = (const uint4*)(A + (size_t)(m0 + r) * 256 + kh * 128 + sgm * 32);
      uint4* dst = (uint4*)(&As[r][sgm * 32]);
      #pragma unroll
      for (int q = 0; q < 4; ++q) dst[q] = src[q];
    }
    {
      int r = tid >> 1, hf = tid & 1;
      const uint4* src = (const uint4*)(W + (size_t)(n0 + r) * 256 + kh * 128 + hf * 64);
      uint4* dst = (uint4*)(&Ws[r][hf * 64]);
      #pragma unroll
      for (int q = 0; q < 8; ++q) dst[q] = src[q];
    }
    __syncthreads();
    #pragma unroll
    for (int kk = 0; kk < 4; ++kk) {
      int k0 = kk * 32;
      f16x8 a = load_frag(&As[w * 16 + lr][0], k0, g4);
      #pragma unroll
      for (int nt = 0; nt < 8; ++nt) {
        f16x8 bf = load_frag(&Ws[nt * 16 + lr][0], k0, g4);
        acc[nt] = __builtin_amdgcn_mfma_f32_16x16x32_f16(a, bf, acc[nt], 0, 0, 0);
      }
    }
    __syncthreads();
  }
  int row4 = (l >> 4) * 4;
  #pragma unroll
  for (int nt = 0; nt < 8; ++nt) {
    int n = n0 + nt * 16 + lr;
    float bv = bias[n];
    #pragma unroll
    for (int reg = 0; reg < 4; ++reg) {
      int m = m0 + w * 16 + row4 + reg;
      P[(size_t)m * 768 + n] = (f16)(acc[nt][reg] + bv);
    }
  }
}

// ---------- K2a: per-segment last-observation summaries ----------
__global__ void k_seg(const float* __restrict__ X, const float* __restrict__ M,
                      float* __restrict__ segX, float* __restrict__ segF) {
  int b = blockIdx.x, s = blockIdx.y, i = threadIdx.x;
  const float* xr = X + ((size_t)(b * I_ + i)) * T_ + s * 128;
  const float* mr = M + ((size_t)(b * I_ + i)) * T_ + s * 128;
  float last = 0.f, seen = 0.f;
  for (int t = 0; t < 128; ++t) {
    float m = mr[t];
    float x = xr[t];
    if (m > 0.f) { last = x; seen = 1.f; }
  }
  segX[((size_t)(b * I_ + i)) * 8 + s] = last;
  segF[((size_t)(b * I_ + i)) * 8 + s] = seen;
}

// ---------- K2b: x_last + double imputation -> AC f16 [BT][256] = [x2 | m] ----------
__global__ void k_x2(const float* __restrict__ X, const float* __restrict__ M,
                     const float* __restrict__ Gx, const float* __restrict__ xmean_p,
                     const float* __restrict__ segX, const float* __restrict__ segF,
                     f16* __restrict__ AC) {
  int b = blockIdx.x, s = blockIdx.y, i = threadIdx.x;
  float xm = xmean_p[0];
  float xl = 0.f;
  const float* sF = segF + ((size_t)(b * I_ + i)) * 8;
  const float* sX = segX + ((size_t)(b * I_ + i)) * 8;
  for (int p = 0; p < s; ++p) { if (sF[p] > 0.f) xl = sX[p]; }
  const float* xr = X + ((size_t)(b * I_ + i)) * T_;
  const float* mr = M + ((size_t)(b * I_ + i)) * T_;
  for (int tl = 0; tl < 128; ++tl) {
    int t = s * 128 + tl;
    float x = xr[t], m = mr[t];
    float gx = Gx[((size_t)(b * T_ + t)) * I_ + i];
    if (m > 0.f) xl = x;  // x_last updated BEFORE imputation (ref order)
    float x1 = m * x + (1.f - m) * (gx * x + (1.f - gx) * xm);
    float x2 = m * x1 + (1.f - m) * (gx * xl + (1.f - gx) * xm);
    size_t o = ((size_t)(b * T_ + t)) * 256;
    AC[o + i] = (f16)x2;
    AC[o + 128 + i] = (f16)m;
  }
}

// ---------- K4: recurrence, 512 threads, three-way weight residency ----------
// Capacity: weights 384 KB = regs 240 KB-target... actual split:
//   regs  : Whr 64 u32 + Whh 56 u32 = 120/thread (law bucket 124-128 at 512 thr;
//           ~30 u32 graceful spill expected, ~60 KB/step scratch, 1/3 of R8)
//   LDS   : Whz full (128 KB, [c4][tid] uint4, conflict-free) + Whh sliver (16 KB)
//           + partR/partZ (partH reuses partR) + hdh/rhdh ~= 156.7 KB
// 2 waves/SIMD hide LDS/scratch latency (R8 precedent).
// P1: r-dots (regs) + z-dots (LDS) — both read hdh. B1.
// P2: lo finish-z (kept in reg), hi finish-r -> rhdh. B2.
// P3: h-dots (regs + LDS sliver) on rhdh -> partR (reused). B3.
// P4: lo finish-h, update h, store, write hdh. B4.
__global__ __launch_bounds__(512, 2) void k_recur10(
    const f16* __restrict__ Gh, const f16* __restrict__ P,
    const uint32_t* __restrict__ blobR, const uint32_t* __restrict__ blobHrg,
    const uint32_t* __restrict__ blobZ4, const uint32_t* __restrict__ blobHl4,
    float* __restrict__ out) {
  __shared__ __align__(16) uint4 whzl[16 * 512];   // 131072 B
  __shared__ __align__(16) uint4 whhl[2 * 512];    //  16384 B
  __shared__ __align__(16) float partR[4][256];    //   4096 B (reused for h-dots)
  __shared__ __align__(16) float partZ[4][256];    //   4096 B
  __shared__ __align__(16) f16 hdh[256];
  __shared__ __align__(16) f16 rhdh[256];
  int tid = threadIdx.x;
  int b = blockIdx.x;
  int ks = tid >> 7, rg = tid & 127;
  bool lo = tid < 256;

  // stage LDS weights (coalesced uint4)
  #pragma unroll
  for (int i = 0; i < 16; ++i) whzl[i * 512 + tid] = ((const uint4*)blobZ4)[i * 512 + tid];
  #pragma unroll
  for (int i = 0; i < 2; ++i)  whhl[i * 512 + tid] = ((const uint4*)blobHl4)[i * 512 + tid];

  uint32_t wR[64], wH[56];
  #pragma unroll
  for (int c = 0; c < 64; ++c) wR[c] = blobR[c * 512 + tid];
  #pragma unroll
  for (int c = 0; c < 56; ++c) wH[c] = blobHrg[c * 512 + tid];

  const f16* gbase = Gh + (size_t)b * T_ * 256;
  const f16* pbase = P + (size_t)b * T_ * 768;
  const f16* ghp = gbase + 2 * 256 + tid;        // gamma(it+2), lo only
  const f16* pzp = pbase + 768 + tid;            // P[it+1][tid], all 512
  const f16* php = pbase + 768 + 512 + tid;      // P[it+1][512+tid], lo only
  float* outp = out + (size_t)b * T_ * 256 + tid;

  float hd_own = 0.f, z_reg = 0.f;
  float pzr_c = (float)pbase[tid];               // P[0][tid] (z for lo, r for hi)
  float ph_c  = lo ? (float)pbase[512 + tid] : 0.f;
  float gh_u  = lo ? (float)gbase[256 + tid] : 0.f;   // gamma(1)
  if (lo) hdh[tid] = (f16)0.f;                   // hd(0) = gamma(0)*h0 = 0
  __syncthreads();

  for (int it = 0; it < T_; ++it) {
    // P1: r-dots (regs) + z-dots (LDS whzl), rows 2rg,2rg+1, k-slice ks
    {
      const uint4* hd4 = (const uint4*)hdh;
      float r0 = 0.f, r1 = 0.f, z0 = 0.f, z1 = 0.f;
      #pragma unroll
      for (int c4 = 0; c4 < 8; ++c4) {
        uint4 hv = hd4[ks * 8 + c4];               // wave-uniform broadcast
        r0 = fdot2_u(wR[c4 * 4 + 0], hv.x, r0);
        r0 = fdot2_u(wR[c4 * 4 + 1], hv.y, r0);
        r0 = fdot2_u(wR[c4 * 4 + 2], hv.z, r0);
        r0 = fdot2_u(wR[c4 * 4 + 3], hv.w, r0);
        r1 = fdot2_u(wR[32 + c4 * 4 + 0], hv.x, r1);
        r1 = fdot2_u(wR[32 + c4 * 4 + 1], hv.y, r1);
        r1 = fdot2_u(wR[32 + c4 * 4 + 2], hv.z, r1);
        r1 = fdot2_u(wR[32 + c4 * 4 + 3], hv.w, r1);
        uint4 wz0 = whzl[c4 * 512 + tid];          // consecutive per lane
        z0 = fdot2_u(wz0.x, hv.x, z0);
        z0 = fdot2_u(wz0.y, hv.y, z0);
        z0 = fdot2_u(wz0.z, hv.z, z0);
        z0 = fdot2_u(wz0.w, hv.w, z0);
        uint4 wz1 = whzl[(8 + c4) * 512 + tid];
        z1 = fdot2_u(wz1.x, hv.x, z1);
        z1 = fdot2_u(wz1.y, hv.y, z1);
        z1 = fdot2_u(wz1.z, hv.z, z1);
        z1 = fdot2_u(wz1.w, hv.w, z1);
        if (c4 & 1) __builtin_amdgcn_sched_barrier(0);
      }
      partR[ks][rg * 2 + 0] = r0;
      partR[ks][rg * 2 + 1] = r1;
      partZ[ks][rg * 2 + 0] = z0;
      partZ[ks][rg * 2 + 1] = z1;
    }
    // prefetch next-iter operands (hidden under P2/P3)
    float pzr_n = 0.f, ph_n = 0.f, gh_n = 0.f;
    if (it + 1 < T_) {
      pzr_n = (float)pzp[0];
      if (lo) ph_n = (float)php[0];
    }
    if (lo && it + 2 < T_) gh_n = (float)ghp[0];
    pzp += 768; php += 768; ghp += 256;
    __syncthreads();  // B1
    // P2: lo finish-z (kept in reg); hi finish-r -> rhdh
    if (lo) {
      z_reg = sigmoidf(pzr_c + partZ[0][tid] + partZ[1][tid] + partZ[2][tid] + partZ[3][tid]);
    } else {
      int row = tid - 256;
      float s = pzr_c + partR[0][row] + partR[1][row] + partR[2][row] + partR[3][row];
      rhdh[row] = (f16)(sigmoidf(s) * (float)hdh[row]);
    }
    __syncthreads();  // B2
    // P3: h-dots on rhdh (wH regs k<56, whhl sliver k 56..64) -> partR (reuse)
    {
      const uint4* rh4 = (const uint4*)rhdh;
      float h0 = 0.f, h1 = 0.f;
      #pragma unroll
      for (int c4 = 0; c4 < 7; ++c4) {
        uint4 rv = rh4[ks * 8 + c4];
        h0 = fdot2_u(wH[c4 * 4 + 0], rv.x, h0);
        h0 = fdot2_u(wH[c4 * 4 + 1], rv.y, h0);
        h0 = fdot2_u(wH[c4 * 4 + 2], rv.z, h0);
        h0 = fdot2_u(wH[c4 * 4 + 3], rv.w, h0);
        h1 = fdot2_u(wH[28 + c4 * 4 + 0], rv.x, h1);
        h1 = fdot2_u(wH[28 + c4 * 4 + 1], rv.y, h1);
        h1 = fdot2_u(wH[28 + c4 * 4 + 2], rv.z, h1);
        h1 = fdot2_u(wH[28 + c4 * 4 + 3], rv.w, h1);
        if (c4 & 1) __builtin_amdgcn_sched_barrier(0);
      }
      {
        uint4 rv = rh4[ks * 8 + 7];
        uint4 wh0 = whhl[0 * 512 + tid];
        h0 = fdot2_u(wh0.x, rv.x, h0);
        h0 = fdot2_u(wh0.y, rv.y, h0);
        h0 = fdot2_u(wh0.z, rv.z, h0);
        h0 = fdot2_u(wh0.w, rv.w, h0);
        uint4 wh1 = whhl[1 * 512 + tid];
        h1 = fdot2_u(wh1.x, rv.x, h1);
        h1 = fdot2_u(wh1.y, rv.y, h1);
        h1 = fdot2_u(wh1.z, rv.z, h1);
        h1 = fdot2_u(wh1.w, rv.w, h1);
      }
      partR[ks][rg * 2 + 0] = h0;
      partR[ks][rg * 2 + 1] = h1;
    }
    __syncthreads();  // B3
    // P4: lo finish-h, update, store, write hd(it+1)
    if (lo) {
      float s2 = ph_c + partR[0][tid] + partR[1][tid] + partR[2][tid] + partR[3][tid];
      float ht = tanh_stable(s2);
      float hnew = (1.f - z_reg) * hd_own + z_reg * ht;
      outp[0] = hnew;
      outp += 256;
      hd_own = gh_u * hnew;
      hdh[tid] = (f16)hd_own;
    }
    pzr_c = pzr_n; ph_c = ph_n; gh_u = gh_n;
    __syncthreads();  // B4 (hdh write vs next-iter P1/P2 readers)
  }
}

// ---------- workspace layout ----------
static constexpr size_t OFF_P  = 0;                          // f16 [BT][768]  = 100663296 B
static constexpr size_t OFF_DT = 0;                          // f16 [BT][128]  (overlay; dead before K3)
static constexpr size_t OFF_GX = 100663296;                  // f32 [BT][128]  = 33554432
static constexpr size_t OFF_GH = OFF_GX + 33554432;          // f16 [BT][256]  = 33554432
static constexpr size_t OFF_AC = OFF_GH + 33554432;          // f16 [BT][256]  = 33554432
static constexpr size_t OFF_WG = OFF_AC + 33554432;          // f16 [384][128] = 98304
static constexpr size_t OFF_BG = OFF_WG + 98304;             // f32 [384]      = 1536
static constexpr size_t OFF_W3 = OFF_BG + 1536;              // f16 [768][256] = 393216
static constexpr size_t OFF_B3 = OFF_W3 + 393216;            // f32 [768]      = 3072
static constexpr size_t OFF_BR = OFF_B3 + 3072;              // u32 [64][512]  = 131072
static constexpr size_t OFF_BH = OFF_BR + 131072;            // u32 [56][512]  = 114688
static constexpr size_t OFF_BZ = OFF_BH + 114688;            // u32 [16*512*4] = 131072
static constexpr size_t OFF_BL = OFF_BZ + 131072;            // u32 [2*512*4]  = 16384
static constexpr size_t OFF_SX = OFF_BL + 16384;             // f32 [B][I][8]  = 262144
static constexpr size_t OFF_SF = OFF_SX + 262144;            // f32 [B][I][8]  = 262144
static constexpr size_t WS_TOTAL = OFF_SF + 262144;          // ~193.4 MiB

extern "C" void kernel_launch(void* const* d_in, const int* in_sizes, int n_in,
                              void* d_out, int out_size, void* d_ws, size_t ws_size,
                              hipStream_t stream) {
  const float* X    = (const float*)d_in[0];
  const float* Mask = (const float*)d_in[1];
  const float* Delta= (const float*)d_in[2];
  const float* xm   = (const float*)d_in[3];
  const float* Wdgx = (const float*)d_in[4];
  const float* bdgx = (const float*)d_in[5];
  const float* Wdgh = (const float*)d_in[6];
  const float* bdgh = (const float*)d_in[7];
  const float* Wxz  = (const float*)d_in[8];
  const float* Whz  = (const float*)d_in[9];
  const float* Wmz  = (const float*)d_in[10];
  const float* bmz  = (const float*)d_in[11];
  const float* Wxr  = (const float*)d_in[12];
  const float* Whr  = (const float*)d_in[13];
  const float* Wmr  = (const float*)d_in[14];
  const float* Wxh  = (const float*)d_in[15];
  const float* Whh  = (const float*)d_in[16];
  const float* Wmh  = (const float*)d_in[17];
  const float* bmh  = (const float*)d_in[18];
  float* out = (float*)d_out;   // f32 output (reference returns float32)
  char* ws = (char*)d_ws;
  if (ws_size < WS_TOTAL) return;  // insufficient scratch: bail cleanly

  f16*      Dt   = (f16*)(ws + OFF_DT);
  f16*      P    = (f16*)(ws + OFF_P);
  float*    Gx   = (float*)(ws + OFF_GX);
  f16*      Gh   = (f16*)(ws + OFF_GH);
  f16*      AC   = (f16*)(ws + OFF_AC);
  f16*      Wg   = (f16*)(ws + OFF_WG);
  float*    bg   = (float*)(ws + OFF_BG);
  f16*      W3   = (f16*)(ws + OFF_W3);
  float*    b3   = (float*)(ws + OFF_B3);
  uint32_t* blR  = (uint32_t*)(ws + OFF_BR);
  uint32_t* blH  = (uint32_t*)(ws + OFF_BH);
  uint32_t* blZ  = (uint32_t*)(ws + OFF_BZ);
  uint32_t* blL  = (uint32_t*)(ws + OFF_BL);
  float*    segX = (float*)(ws + OFF_SX);
  float*    segF = (float*)(ws + OFF_SF);

  k_prep<<<dim3(64), dim3(256), 0, stream>>>(Wdgx, bdgx, Wdgh, bdgh, Wxz, Whz, Wmz, bmz,
                                             Wxr, Whr, Wmr, Wxh, Whh, Wmh, bmh,
                                             Wg, bg, W3, b3, blR, blH, blZ, blL);
  k_transpose_d<<<dim3(16, 2, 64), dim3(64, 4), 0, stream>>>(Delta, Dt);
  k_gemm1<<<dim3(1024, 3), dim3(256), 0, stream>>>(Dt, Wg, bg, Gx, Gh);
  k_seg<<<dim3(64, 8), dim3(128), 0, stream>>>(X, Mask, segX, segF);
  k_x2<<<dim3(64, 8), dim3(128), 0, stream>>>(X, Mask, Gx, xm, segX, segF, AC);
  k_gemm3<<<dim3(1024, 6), dim3(256), 0, stream>>>(AC, W3, b3, P);
  k_recur10<<<dim3(64), dim3(512), 0, stream>>>(Gh, P, blR, blH, blZ, blL, out);
}